// Round 4
// baseline (497.831 us; speedup 1.0000x reference)
//
#include <hip/hip_runtime.h>
#include <math.h>

#define D_    256
#define H_    256
#define R_    8
#define NINIT 8192
#define LL    16
#define MM    4096
#define NTOT  (NINIT + LL*MM)   // 73728
#define TB    16                // nodes per MFMA tile/block
#define MP    (MM + R_*TB)      // 4224 padded slots per layer
#define NB    (MP/TB)           // 264 blocks per layer
#define KS1   16                // K-steps GEMM1 (512/32)
#define KS2   8                 // K-steps GEMM2 (256/32)
#define NT    16                // n-tiles (256/16)
#define EVB   16                // nodes per eval block
#define GE    (NTOT/EVB)        // 4608

typedef __attribute__((ext_vector_type(8))) short short8;
typedef __attribute__((ext_vector_type(4))) float f32x4;

__device__ __forceinline__ uint bf16h(float f) {           // f32 -> bf16 bits (RNE)
    uint u = __float_as_uint(f);
    return (u + 0x7fffu + ((u >> 16) & 1u)) >> 16;
}
__device__ __forceinline__ float bf16f(uint h) { return __uint_as_float(h << 16); }

// ---------------- counting sort by rule (per layer), bins padded to TB ----------------
__global__ __launch_bounds__(256) void sort_kernel(const int* __restrict__ rule,
                                                   int* __restrict__ sorted) {
    int l = blockIdx.x, t = threadIdx.x;
    __shared__ int hist[R_], cursor[R_];
    if (t < R_) hist[t] = 0;
    __syncthreads();
    for (int m = t; m < MM; m += 256) atomicAdd(&hist[rule[l*MM + m]], 1);
    __syncthreads();
    if (t == 0) {
        int off = 0;
        for (int r = 0; r < R_; r++) { cursor[r] = off; off += ((hist[r] + TB - 1)/TB)*TB; }
    }
    for (int m = t; m < MP; m += 256) sorted[l*MP + m] = -1;
    __syncthreads();
    for (int m = t; m < MM; m += 256) {
        int r = rule[l*MM + m];
        int pos = atomicAdd(&cursor[r], 1);
        sorted[l*MP + pos] = m;
    }
}

// ---------------- init embeddings ----------------
__global__ __launch_bounds__(256) void embed_kernel(const float* __restrict__ itab,
                                                    const float* __restrict__ stab,
                                                    const int* __restrict__ thax,
                                                    const int* __restrict__ sine,
                                                    float* __restrict__ store) {
    int gid = blockIdx.x*256 + threadIdx.x;
    int n = gid >> 6, d = (gid & 63) << 2;
    int th = thax[n], si = sine[n];
    const float4 a = *(const float4*)&itab[th*D_ + d];
    const float4 b = *(const float4*)&stab[si*D_ + d];
    float4 o; o.x = a.x+b.x; o.y = a.y+b.y; o.z = a.z+b.z; o.w = a.w+b.w;
    *(float4*)&store[(size_t)n*D_ + d] = o;
}

// ---------------- pack weights into fragment-linear bf16 hi/lo tiles ----------------
// Ph[((r*KSn + ks)*NT + nt)*64 + lane][j] = bf16(W[r][ks*32 + (lane>>4)*8 + j][nt*16 + (lane&15)])
__global__ __launch_bounds__(256) void pack_kernel(const float* __restrict__ W,
        ushort* __restrict__ Ph, ushort* __restrict__ Pl, int KSn) {
    int gid = blockIdx.x*256 + threadIdx.x;     // flat (r,ks,nt,lane)
    int lane = gid & 63;
    int nt   = (gid >> 6) & 15;
    int ks   = (gid >> 10) % KSn;
    int r    = gid / (1024*KSn);
    int K = KSn*32;
    int k0 = ks*32 + (lane >> 4)*8;
    int c  = nt*16 + (lane & 15);
    const float* src = W + ((size_t)r*K + k0)*256 + c;
    uint h[8], lo[8];
    #pragma unroll
    for (int j = 0; j < 8; j++) {
        float w = src[(size_t)j*256];
        h[j] = bf16h(w);
        lo[j] = bf16h(w - bf16f(h[j]));
    }
    size_t o = (size_t)gid*8;
    *(uint4*)&Ph[o] = make_uint4(h[0]|(h[1]<<16),  h[2]|(h[3]<<16),  h[4]|(h[5]<<16),  h[6]|(h[7]<<16));
    *(uint4*)&Pl[o] = make_uint4(lo[0]|(lo[1]<<16), lo[2]|(lo[3]<<16), lo[4]|(lo[5]<<16), lo[6]|(lo[7]<<16));
}

// ---------------- one DAG layer: 16-node tile, MFMA 3-pass split-bf16 ----------------
__global__ __launch_bounds__(256) void layer_kernel(float* __restrict__ store,
        const int* __restrict__ sorted, const int* __restrict__ rule,
        const int* __restrict__ parents,
        const ushort* __restrict__ P1h, const ushort* __restrict__ P1l,
        const ushort* __restrict__ P2h, const ushort* __restrict__ P2l,
        const float* __restrict__ b1, const float* __restrict__ t1,
        const float* __restrict__ b2, const float* __restrict__ pt, int l) {
    __shared__ ushort Xh[TB*512], Xl[TB*512];   // 16 rows x 512 bf16 (hi/lo), swizzled
    __shared__ ushort Hh[TB*256], Hl[TB*256];
    __shared__ int idx_s[TB];
    const int t = threadIdx.x, lane = t & 63, wv = t >> 6;
    if (t < TB) idx_s[t] = sorted[l*MP + blockIdx.x*TB + t];
    __syncthreads();
    if (idx_s[0] < 0) return;                   // fully-padded tail block
    const int r = rule[l*MM + idx_s[0]];

    // ---- stage X: wave wv covers rows 4wv..4wv+3; 2 rows x quarter per iter ----
    for (int it = 0; it < 8; it++) {
        int row = wv*4 + (it >> 2)*2 + (lane >> 5);
        int q   = it & 3;                        // quarter of the 512-wide row
        int idx = idx_s[row];
        float4 v = make_float4(0.f, 0.f, 0.f, 0.f);
        if (idx >= 0) {
            int p = parents[(l*MM + idx)*2 + (q >> 1)];
            v = *(const float4*)&store[(size_t)p*256 + (q & 1)*128 + (lane & 31)*4];
        }
        uint h0 = bf16h(v.x), h1 = bf16h(v.y), h2 = bf16h(v.z), h3 = bf16h(v.w);
        uint l0 = bf16h(v.x - bf16f(h0)), l1 = bf16h(v.y - bf16f(h1));
        uint l2 = bf16h(v.z - bf16f(h2)), l3 = bf16h(v.w - bf16f(h3));
        int e = q*128 + (lane & 31)*4;           // element within 512-wide row
        int boff = (e*2) ^ ((row & 7) << 4);     // swizzled byte offset in row
        *(uint2*)&Xh[row*512 + (boff >> 1)] = make_uint2(h0|(h1<<16), h2|(h3<<16));
        *(uint2*)&Xl[row*512 + (boff >> 1)] = make_uint2(l0|(l1<<16), l2|(l3<<16));
    }
    __syncthreads();

    const int crow = lane & 15, kg = lane >> 4;
    const float tw = pt[1];

    // ---- GEMM1: [16x512] @ W1[512x256], 3-pass split-bf16 ----
    f32x4 acc[4];
    #pragma unroll
    for (int nt = 0; nt < 4; nt++) {
        int col = (wv*4 + nt)*16 + crow;
        float bb = b1[r*H_ + col] + tw * t1[r*H_ + col];
        acc[nt] = (f32x4){bb, bb, bb, bb};
    }
    const short8* B1h = (const short8*)P1h + (size_t)r*KS1*NT*64;
    const short8* B1l = (const short8*)P1l + (size_t)r*KS1*NT*64;
    #pragma unroll 4
    for (int ks = 0; ks < KS1; ks++) {
        int ab = ((ks*64 + kg*16) ^ ((crow & 7) << 4)) >> 1;
        short8 xh = *(const short8*)&Xh[crow*512 + ab];
        short8 xl = *(const short8*)&Xl[crow*512 + ab];
        #pragma unroll
        for (int nt = 0; nt < 4; nt++) {
            size_t ti = (size_t)(ks*NT + wv*4 + nt)*64 + lane;
            short8 bh = B1h[ti], bl = B1l[ti];
            acc[nt] = __builtin_amdgcn_mfma_f32_16x16x32_bf16(xl, bh, acc[nt], 0, 0, 0);
            acc[nt] = __builtin_amdgcn_mfma_f32_16x16x32_bf16(xh, bl, acc[nt], 0, 0, 0);
            acc[nt] = __builtin_amdgcn_mfma_f32_16x16x32_bf16(xh, bh, acc[nt], 0, 0, 0);
        }
    }
    // relu + split to bf16 hi/lo H (swizzled)
    #pragma unroll
    for (int nt = 0; nt < 4; nt++) {
        int col = (wv*4 + nt)*16 + crow;
        #pragma unroll
        for (int reg = 0; reg < 4; reg++) {
            int row = kg*4 + reg;
            float h = fmaxf(acc[nt][reg], 0.f);
            uint hh = bf16h(h);
            uint hl = bf16h(h - bf16f(hh));
            int boff = (col*2) ^ ((row & 7) << 4);
            Hh[row*256 + (boff >> 1)] = (ushort)hh;
            Hl[row*256 + (boff >> 1)] = (ushort)hl;
        }
    }
    __syncthreads();

    // ---- GEMM2: [16x256] @ W2[256x256], 3-pass split-bf16 ----
    f32x4 acc2[4];
    #pragma unroll
    for (int nt = 0; nt < 4; nt++) {
        int col = (wv*4 + nt)*16 + crow;
        float bb = b2[r*D_ + col];
        acc2[nt] = (f32x4){bb, bb, bb, bb};
    }
    const short8* B2h = (const short8*)P2h + (size_t)r*KS2*NT*64;
    const short8* B2l = (const short8*)P2l + (size_t)r*KS2*NT*64;
    #pragma unroll 4
    for (int ks = 0; ks < KS2; ks++) {
        int ab = ((ks*64 + kg*16) ^ ((crow & 7) << 4)) >> 1;
        short8 hh = *(const short8*)&Hh[crow*256 + ab];
        short8 hl = *(const short8*)&Hl[crow*256 + ab];
        #pragma unroll
        for (int nt = 0; nt < 4; nt++) {
            size_t ti = (size_t)(ks*NT + wv*4 + nt)*64 + lane;
            short8 bh = B2h[ti], bl = B2l[ti];
            acc2[nt] = __builtin_amdgcn_mfma_f32_16x16x32_bf16(hl, bh, acc2[nt], 0, 0, 0);
            acc2[nt] = __builtin_amdgcn_mfma_f32_16x16x32_bf16(hh, bl, acc2[nt], 0, 0, 0);
            acc2[nt] = __builtin_amdgcn_mfma_f32_16x16x32_bf16(hh, bh, acc2[nt], 0, 0, 0);
        }
    }
    // ---- store y (f32) to computed node rows ----
    const int ob = NINIT + l*MM;
    #pragma unroll
    for (int nt = 0; nt < 4; nt++) {
        int col = (wv*4 + nt)*16 + crow;
        #pragma unroll
        for (int reg = 0; reg < 4; reg++) {
            int row = kg*4 + reg;
            int idx = idx_s[row];
            if (idx >= 0) store[(size_t)(ob + idx)*256 + col] = acc2[nt][reg];
        }
    }
}

// ---------------- eval_net + loss partials ----------------
__global__ __launch_bounds__(256) void eval_kernel(const float* __restrict__ store,
        const float* __restrict__ w_eval, const float* __restrict__ b_eval,
        const float* __restrict__ t_eval, const float* __restrict__ pt,
        const float* __restrict__ pos, const float* __restrict__ neg,
        const int* __restrict__ labeled, float* __restrict__ partials) {
    int t = threadIdx.x, lane = t & 63, wv = t >> 6;
    const float4 w4 = *(const float4*)&w_eval[lane*4];
    const float bev = b_eval[0] + pt[0]*t_eval[0];
    float A = 0.f, B = 0.f, pOK = 0.f, nOK = 0.f;
    int n0 = blockIdx.x * EVB;
    #pragma unroll
    for (int k = 0; k < 4; k++) {
        int n = n0 + wv*4 + k;
        const float4 s = *(const float4*)&store[(size_t)n*D_ + lane*4];
        float d = s.x*w4.x + s.y*w4.y + s.z*w4.z + s.w*w4.w;
        #pragma unroll
        for (int off = 32; off > 0; off >>= 1) d += __shfl_xor(d, off);
        if (lane == 0) {
            float val = d + bev;
            float lab = (float)labeled[n];
            float p = pos[n], ng = neg[n];
            float tot = p + ng;
            float target = p / fmaxf(tot, 1e-8f);
            float ls  = (val >= 0.f) ? -log1pf(expf(-val)) : (val  - log1pf(expf( val)));
            float lns = (val <= 0.f) ? -log1pf(expf( val)) : (-val - log1pf(expf(-val)));
            A += lab*tot*target*ls;
            B += lab*tot*(1.f - target)*lns;
            if (val >= 0.f) pOK += lab*p; else nOK += lab*ng;
        }
    }
    float tp = 0.f, tn = 0.f;
    if (t < EVB) {
        int n = n0 + t;
        float lab2 = (float)labeled[n];
        tp = pos[n]*lab2; tn = neg[n]*lab2;
    }
    __shared__ float red[256];
    #define BRED(VAL, J) { __syncthreads(); red[t] = (VAL); __syncthreads();              \
        for (int s_ = 128; s_ > 0; s_ >>= 1) { if (t < s_) red[t] += red[t+s_]; __syncthreads(); } \
        if (t == 0) partials[blockIdx.x*6 + (J)] = red[0]; }
    BRED(A, 0) BRED(B, 1) BRED(pOK, 2) BRED(nOK, 3) BRED(tp, 4) BRED(tn, 5)
    #undef BRED
}

// ---------------- final reduce + pw + loss ----------------
__global__ __launch_bounds__(256) void final_kernel(const float* __restrict__ partials,
                                                    float* __restrict__ out) {
    int t = threadIdx.x;
    float sA=0.f, sB=0.f, sP=0.f, sN=0.f, sTP=0.f, sTN=0.f;
    for (int g = t; g < GE; g += 256) {
        sA  += partials[g*6+0]; sB  += partials[g*6+1]; sP  += partials[g*6+2];
        sN  += partials[g*6+3]; sTP += partials[g*6+4]; sTN += partials[g*6+5];
    }
    __shared__ float red[256];
    #define FRED(V) { __syncthreads(); red[t] = (V); __syncthreads();                     \
        for (int s_ = 128; s_ > 0; s_ >>= 1) { if (t < s_) red[t] += red[t+s_]; __syncthreads(); } \
        (V) = red[0]; __syncthreads(); }
    FRED(sA) FRED(sB) FRED(sP) FRED(sN) FRED(sTP) FRED(sTN)
    #undef FRED
    if (t == 0) {
        float pw = sTN / fmaxf(sTP, 1e-8f);
        out[0] = -(pw*sA + sB);
        out[1] = sP; out[2] = sN; out[3] = sTP; out[4] = sTN;
    }
}

extern "C" void kernel_launch(void* const* d_in, const int* in_sizes, int n_in,
                              void* d_out, int out_size, void* d_ws, size_t ws_size,
                              hipStream_t stream) {
    const float* pt        = (const float*)d_in[0];
    const float* init_tab  = (const float*)d_in[1];
    const float* sine_tab  = (const float*)d_in[2];
    const float* W1        = (const float*)d_in[3];
    const float* b1        = (const float*)d_in[4];
    const float* t1        = (const float*)d_in[5];
    const float* W2        = (const float*)d_in[6];
    const float* b2        = (const float*)d_in[7];
    const float* w_eval    = (const float*)d_in[8];
    const float* b_eval    = (const float*)d_in[9];
    const float* t_eval    = (const float*)d_in[10];
    const float* pos       = (const float*)d_in[11];
    const float* neg       = (const float*)d_in[12];
    const int*   init_thax = (const int*)d_in[13];
    const int*   init_sine = (const int*)d_in[14];
    const int*   drule     = (const int*)d_in[15];
    const int*   dparents  = (const int*)d_in[16];
    const int*   labeled   = (const int*)d_in[17];
    float* out = (float*)d_out;

    // workspace layout (bytes, all 16-aligned)
    char* w = (char*)d_ws;
    const size_t STORE_B = (size_t)NTOT * D_ * 4;            // 75,497,472
    const size_t SORT_B  = (size_t)LL * MP * 4;              //    270,336
    const size_t P1_B    = (size_t)R_*KS1*NT*64*8*2;         //  2,097,152 each
    const size_t P2_B    = (size_t)R_*KS2*NT*64*8*2;         //  1,048,576 each
    float*  store    = (float*) w;                    w += STORE_B;
    int*    sorted   = (int*)   w;                    w += SORT_B;
    ushort* P1h      = (ushort*)w;                    w += P1_B;
    ushort* P1l      = (ushort*)w;                    w += P1_B;
    ushort* P2h      = (ushort*)w;                    w += P2_B;
    ushort* P2l      = (ushort*)w;                    w += P2_B;
    float*  partials = (float*) w;                    // GE*6*4 = 110,592

    sort_kernel <<<LL,   256, 0, stream>>>(drule, sorted);
    embed_kernel<<<NINIT*64/256, 256, 0, stream>>>(init_tab, sine_tab, init_thax, init_sine, store);
    pack_kernel <<<R_*KS1*NT*64/256, 256, 0, stream>>>(W1, P1h, P1l, KS1);   // 512 blocks
    pack_kernel <<<R_*KS2*NT*64/256, 256, 0, stream>>>(W2, P2h, P2l, KS2);   // 256 blocks
    for (int l = 0; l < LL; l++)
        layer_kernel<<<NB, 256, 0, stream>>>(store, sorted, drule, dparents,
                                             P1h, P1l, P2h, P2l, b1, t1, b2, pt, l);
    eval_kernel <<<GE, 256, 0, stream>>>(store, w_eval, b_eval, t_eval, pt,
                                         pos, neg, labeled, partials);
    final_kernel<<<1,  256, 0, stream>>>(partials, out);
}

// Round 5
// 344.706 us; speedup vs baseline: 1.4442x; 1.4442x over previous
//
#include <hip/hip_runtime.h>
#include <math.h>

#define D_    256
#define H_    256
#define R_    8
#define NINIT 8192
#define LL    16
#define MM    4096
#define NTOT  (NINIT + LL*MM)   // 73728
#define TB    16                // nodes per MFMA tile/block
#define MP    (MM + R_*TB)      // 4224 padded slots per layer
#define NB    (MP/TB)           // 264 blocks per layer
#define KS1   16                // K-steps GEMM1 (512/32)
#define KS2   8                 // K-steps GEMM2 (256/32)
#define NT    16                // n-tiles (256/16)
#define EVB   16                // nodes per eval block
#define GE    (NTOT/EVB)        // 4608

#define EMB_BLKS (NINIT*64/256)        // 2048
#define PK1_BLKS (R_*KS1*NT*64/256)    // 512
#define PK2_BLKS (R_*KS2*NT*64/256)    // 256
#define PREP_BLKS (LL + EMB_BLKS + PK1_BLKS + PK2_BLKS)

typedef __attribute__((ext_vector_type(8))) short short8;
typedef __attribute__((ext_vector_type(4))) float f32x4;

__device__ __forceinline__ uint bf16h(float f) {           // f32 -> bf16 bits (RNE)
    uint u = __float_as_uint(f);
    return (u + 0x7fffu + ((u >> 16) & 1u)) >> 16;
}
__device__ __forceinline__ float bf16f(uint h) { return __uint_as_float(h << 16); }

// ---------------- prep bodies ----------------
__device__ void sort_body(int l, int t, const int* __restrict__ rule,
                          int* __restrict__ sorted) {
    __shared__ int hist[R_], cursor[R_];
    if (t < R_) hist[t] = 0;
    __syncthreads();
    for (int m = t; m < MM; m += 256) atomicAdd(&hist[rule[l*MM + m]], 1);
    __syncthreads();
    if (t == 0) {
        int off = 0;
        for (int r = 0; r < R_; r++) { cursor[r] = off; off += ((hist[r] + TB - 1)/TB)*TB; }
    }
    for (int m = t; m < MP; m += 256) sorted[l*MP + m] = -1;
    __syncthreads();
    for (int m = t; m < MM; m += 256) {
        int r = rule[l*MM + m];
        int pos = atomicAdd(&cursor[r], 1);
        sorted[l*MP + pos] = m;
    }
}

__device__ void embed_body(int gid, const float* __restrict__ itab,
                           const float* __restrict__ stab,
                           const int* __restrict__ thax, const int* __restrict__ sine,
                           float* __restrict__ store) {
    int n = gid >> 6, d = (gid & 63) << 2;
    int th = thax[n], si = sine[n];
    const float4 a = *(const float4*)&itab[th*D_ + d];
    const float4 b = *(const float4*)&stab[si*D_ + d];
    float4 o; o.x = a.x+b.x; o.y = a.y+b.y; o.z = a.z+b.z; o.w = a.w+b.w;
    *(float4*)&store[(size_t)n*D_ + d] = o;
}

// Ph[((r*KSn + ks)*NT + nt)*64 + lane][j] = bf16(W[r][ks*32 + (lane>>4)*8 + j][nt*16 + (lane&15)])
__device__ void pack_body(int gid, const float* __restrict__ W,
                          ushort* __restrict__ Ph, ushort* __restrict__ Pl, int KSn) {
    int lane = gid & 63;
    int nt   = (gid >> 6) & 15;
    int ks   = (gid >> 10) % KSn;
    int r    = gid / (1024*KSn);
    int K = KSn*32;
    int k0 = ks*32 + (lane >> 4)*8;
    int c  = nt*16 + (lane & 15);
    const float* src = W + ((size_t)r*K + k0)*256 + c;
    uint h[8], lo[8];
    #pragma unroll
    for (int j = 0; j < 8; j++) {
        float w = src[(size_t)j*256];
        h[j] = bf16h(w);
        lo[j] = bf16h(w - bf16f(h[j]));
    }
    size_t o = (size_t)gid*8;
    *(uint4*)&Ph[o] = make_uint4(h[0]|(h[1]<<16),  h[2]|(h[3]<<16),  h[4]|(h[5]<<16),  h[6]|(h[7]<<16));
    *(uint4*)&Pl[o] = make_uint4(lo[0]|(lo[1]<<16), lo[2]|(lo[3]<<16), lo[4]|(lo[5]<<16), lo[6]|(lo[7]<<16));
}

__global__ __launch_bounds__(256) void prep_kernel(
        const int* __restrict__ drule, int* __restrict__ sorted,
        const float* __restrict__ itab, const float* __restrict__ stab,
        const int* __restrict__ thax, const int* __restrict__ sine,
        float* __restrict__ store,
        const float* __restrict__ W1, ushort* __restrict__ P1h, ushort* __restrict__ P1l,
        const float* __restrict__ W2, ushort* __restrict__ P2h, ushort* __restrict__ P2l) {
    int b = blockIdx.x, t = threadIdx.x;
    if (b < LL) {
        sort_body(b, t, drule, sorted);
    } else if (b < LL + EMB_BLKS) {
        embed_body((b - LL)*256 + t, itab, stab, thax, sine, store);
    } else if (b < LL + EMB_BLKS + PK1_BLKS) {
        pack_body((b - LL - EMB_BLKS)*256 + t, W1, P1h, P1l, KS1);
    } else {
        pack_body((b - LL - EMB_BLKS - PK1_BLKS)*256 + t, W2, P2h, P2l, KS2);
    }
}

// ---------------- one DAG layer: 16-node tile, 16 waves, 1 n-tile per wave ----------------
__global__ __launch_bounds__(1024) void layer_kernel(float* __restrict__ store,
        const int* __restrict__ sorted, const int* __restrict__ rule,
        const int* __restrict__ parents,
        const ushort* __restrict__ P1h, const ushort* __restrict__ P1l,
        const ushort* __restrict__ P2h, const ushort* __restrict__ P2l,
        const float* __restrict__ b1, const float* __restrict__ t1,
        const float* __restrict__ b2, const float* __restrict__ pt, int l) {
    __shared__ ushort Xh[TB*512], Xl[TB*512];   // 16 rows x 512 bf16 hi/lo, swizzled
    __shared__ ushort Hh[TB*256], Hl[TB*256];
    __shared__ int idx_s[TB];
    const int t = threadIdx.x, lane = t & 63, wv = t >> 6;   // wv = 0..15
    if (t < TB) idx_s[t] = sorted[l*MP + blockIdx.x*TB + t];
    __syncthreads();
    if (idx_s[0] < 0) return;                   // fully-padded tail block
    const int r = rule[l*MM + idx_s[0]];
    const float tw = pt[1];

    // ---- stage X: wave wv stages row wv (one parent half per iter, float4/lane) ----
    {
        const int row = wv;
        const int idx = idx_s[row];
        #pragma unroll
        for (int half = 0; half < 2; half++) {
            float4 v = make_float4(0.f, 0.f, 0.f, 0.f);
            if (idx >= 0) {
                int p = parents[(l*MM + idx)*2 + half];
                v = *(const float4*)&store[(size_t)p*D_ + lane*4];
            }
            uint h0 = bf16h(v.x), h1 = bf16h(v.y), h2 = bf16h(v.z), h3 = bf16h(v.w);
            uint l0 = bf16h(v.x - bf16f(h0)), l1 = bf16h(v.y - bf16f(h1));
            uint l2 = bf16h(v.z - bf16f(h2)), l3 = bf16h(v.w - bf16f(h3));
            int e = half*256 + lane*4;
            int boff = (e*2) ^ ((row & 7) << 4);
            *(uint2*)&Xh[row*512 + (boff >> 1)] = make_uint2(h0|(h1<<16), h2|(h3<<16));
            *(uint2*)&Xl[row*512 + (boff >> 1)] = make_uint2(l0|(l1<<16), l2|(l3<<16));
        }
    }
    __syncthreads();

    const int crow = lane & 15, kg = lane >> 4;
    const int col = wv*16 + crow;

    // ---- GEMM1: [16x512] @ W1[512x256], 3-pass split-bf16; wave owns n-tile wv ----
    f32x4 acc;
    { float bb = b1[r*H_ + col] + tw * t1[r*H_ + col]; acc = (f32x4){bb, bb, bb, bb}; }
    const short8* B1hp = (const short8*)P1h + ((size_t)r*KS1*NT + wv)*64 + lane;
    const short8* B1lp = (const short8*)P1l + ((size_t)r*KS1*NT + wv)*64 + lane;
    #pragma unroll
    for (int ks = 0; ks < KS1; ks++) {
        int ab = ((ks*64 + kg*16) ^ ((crow & 7) << 4)) >> 1;
        short8 xh = *(const short8*)&Xh[crow*512 + ab];
        short8 xl = *(const short8*)&Xl[crow*512 + ab];
        short8 bh = B1hp[(size_t)ks*NT*64];
        short8 bl = B1lp[(size_t)ks*NT*64];
        acc = __builtin_amdgcn_mfma_f32_16x16x32_bf16(xl, bh, acc, 0, 0, 0);
        acc = __builtin_amdgcn_mfma_f32_16x16x32_bf16(xh, bl, acc, 0, 0, 0);
        acc = __builtin_amdgcn_mfma_f32_16x16x32_bf16(xh, bh, acc, 0, 0, 0);
    }
    // relu + split to bf16 hi/lo H (swizzled)
    #pragma unroll
    for (int reg = 0; reg < 4; reg++) {
        int row = kg*4 + reg;
        float h = fmaxf(acc[reg], 0.f);
        uint hh = bf16h(h);
        uint hl = bf16h(h - bf16f(hh));
        int boff = (col*2) ^ ((row & 7) << 4);
        Hh[row*256 + (boff >> 1)] = (ushort)hh;
        Hl[row*256 + (boff >> 1)] = (ushort)hl;
    }
    __syncthreads();

    // ---- GEMM2: [16x256] @ W2[256x256], 3-pass split-bf16; wave owns n-tile wv ----
    f32x4 acc2;
    { float bb = b2[r*D_ + col]; acc2 = (f32x4){bb, bb, bb, bb}; }
    const short8* B2hp = (const short8*)P2h + ((size_t)r*KS2*NT + wv)*64 + lane;
    const short8* B2lp = (const short8*)P2l + ((size_t)r*KS2*NT + wv)*64 + lane;
    #pragma unroll
    for (int ks = 0; ks < KS2; ks++) {
        int ab = ((ks*64 + kg*16) ^ ((crow & 7) << 4)) >> 1;
        short8 hh = *(const short8*)&Hh[crow*256 + ab];
        short8 hl = *(const short8*)&Hl[crow*256 + ab];
        short8 bh = B2hp[(size_t)ks*NT*64];
        short8 bl = B2lp[(size_t)ks*NT*64];
        acc2 = __builtin_amdgcn_mfma_f32_16x16x32_bf16(hl, bh, acc2, 0, 0, 0);
        acc2 = __builtin_amdgcn_mfma_f32_16x16x32_bf16(hh, bl, acc2, 0, 0, 0);
        acc2 = __builtin_amdgcn_mfma_f32_16x16x32_bf16(hh, bh, acc2, 0, 0, 0);
    }
    // ---- store y (f32) ----
    const int ob = NINIT + l*MM;
    #pragma unroll
    for (int reg = 0; reg < 4; reg++) {
        int row = kg*4 + reg;
        int idx = idx_s[row];
        if (idx >= 0) store[(size_t)(ob + idx)*D_ + col] = acc2[reg];
    }
}

// ---------------- eval_net + loss partials ----------------
__global__ __launch_bounds__(256) void eval_kernel(const float* __restrict__ store,
        const float* __restrict__ w_eval, const float* __restrict__ b_eval,
        const float* __restrict__ t_eval, const float* __restrict__ pt,
        const float* __restrict__ pos, const float* __restrict__ neg,
        const int* __restrict__ labeled, float* __restrict__ partials) {
    int t = threadIdx.x, lane = t & 63, wv = t >> 6;
    const float4 w4 = *(const float4*)&w_eval[lane*4];
    const float bev = b_eval[0] + pt[0]*t_eval[0];
    float A = 0.f, B = 0.f, pOK = 0.f, nOK = 0.f, tp = 0.f, tn = 0.f;
    int n0 = blockIdx.x * EVB;
    #pragma unroll
    for (int k = 0; k < 4; k++) {
        int n = n0 + wv*4 + k;
        const float4 s = *(const float4*)&store[(size_t)n*D_ + lane*4];
        float d = s.x*w4.x + s.y*w4.y + s.z*w4.z + s.w*w4.w;
        #pragma unroll
        for (int off = 32; off > 0; off >>= 1) d += __shfl_xor(d, off);
        if (lane == 0) {
            float val = d + bev;
            float lab = (float)labeled[n];
            float p = pos[n], ng = neg[n];
            float tot = p + ng;
            float target = p / fmaxf(tot, 1e-8f);
            float ls  = (val >= 0.f) ? -log1pf(expf(-val)) : (val  - log1pf(expf( val)));
            float lns = (val <= 0.f) ? -log1pf(expf( val)) : (-val - log1pf(expf(-val)));
            A += lab*tot*target*ls;
            B += lab*tot*(1.f - target)*lns;
            if (val >= 0.f) pOK += lab*p; else nOK += lab*ng;
            tp += p*lab; tn += ng*lab;
        }
    }
    __shared__ float red[4][6];
    if (lane == 0) {
        red[wv][0] = A;  red[wv][1] = B;  red[wv][2] = pOK;
        red[wv][3] = nOK; red[wv][4] = tp; red[wv][5] = tn;
    }
    __syncthreads();
    if (t < 6) partials[blockIdx.x*6 + t] = red[0][t] + red[1][t] + red[2][t] + red[3][t];
}

// ---------------- final reduce + pw + loss ----------------
__global__ __launch_bounds__(256) void final_kernel(const float* __restrict__ partials,
                                                    float* __restrict__ out) {
    int t = threadIdx.x;
    float sA=0.f, sB=0.f, sP=0.f, sN=0.f, sTP=0.f, sTN=0.f;
    for (int g = t; g < GE; g += 256) {
        sA  += partials[g*6+0]; sB  += partials[g*6+1]; sP  += partials[g*6+2];
        sN  += partials[g*6+3]; sTP += partials[g*6+4]; sTN += partials[g*6+5];
    }
    __shared__ float red[256];
    #define FRED(V) { __syncthreads(); red[t] = (V); __syncthreads();                     \
        for (int s_ = 128; s_ > 0; s_ >>= 1) { if (t < s_) red[t] += red[t+s_]; __syncthreads(); } \
        (V) = red[0]; __syncthreads(); }
    FRED(sA) FRED(sB) FRED(sP) FRED(sN) FRED(sTP) FRED(sTN)
    #undef FRED
    if (t == 0) {
        float pw = sTN / fmaxf(sTP, 1e-8f);
        out[0] = -(pw*sA + sB);
        out[1] = sP; out[2] = sN; out[3] = sTP; out[4] = sTN;
    }
}

extern "C" void kernel_launch(void* const* d_in, const int* in_sizes, int n_in,
                              void* d_out, int out_size, void* d_ws, size_t ws_size,
                              hipStream_t stream) {
    const float* pt        = (const float*)d_in[0];
    const float* init_tab  = (const float*)d_in[1];
    const float* sine_tab  = (const float*)d_in[2];
    const float* W1        = (const float*)d_in[3];
    const float* b1        = (const float*)d_in[4];
    const float* t1        = (const float*)d_in[5];
    const float* W2        = (const float*)d_in[6];
    const float* b2        = (const float*)d_in[7];
    const float* w_eval    = (const float*)d_in[8];
    const float* b_eval    = (const float*)d_in[9];
    const float* t_eval    = (const float*)d_in[10];
    const float* pos       = (const float*)d_in[11];
    const float* neg       = (const float*)d_in[12];
    const int*   init_thax = (const int*)d_in[13];
    const int*   init_sine = (const int*)d_in[14];
    const int*   drule     = (const int*)d_in[15];
    const int*   dparents  = (const int*)d_in[16];
    const int*   labeled   = (const int*)d_in[17];
    float* out = (float*)d_out;

    // workspace layout (bytes, all 16-aligned)
    char* w = (char*)d_ws;
    const size_t STORE_B = (size_t)NTOT * D_ * 4;            // 75,497,472
    const size_t SORT_B  = (size_t)LL * MP * 4;              //    270,336
    const size_t P1_B    = (size_t)R_*KS1*NT*64*8*2;         //  2,097,152 each
    const size_t P2_B    = (size_t)R_*KS2*NT*64*8*2;         //  1,048,576 each
    float*  store    = (float*) w;                    w += STORE_B;
    int*    sorted   = (int*)   w;                    w += SORT_B;
    ushort* P1h      = (ushort*)w;                    w += P1_B;
    ushort* P1l      = (ushort*)w;                    w += P1_B;
    ushort* P2h      = (ushort*)w;                    w += P2_B;
    ushort* P2l      = (ushort*)w;                    w += P2_B;
    float*  partials = (float*) w;                    // GE*6*4 = 110,592

    prep_kernel<<<PREP_BLKS, 256, 0, stream>>>(drule, sorted, init_tab, sine_tab,
                                               init_thax, init_sine, store,
                                               W1, P1h, P1l, W2, P2h, P2l);
    for (int l = 0; l < LL; l++)
        layer_kernel<<<NB, 1024, 0, stream>>>(store, sorted, drule, dparents,
                                              P1h, P1l, P2h, P2l, b1, t1, b2, pt, l);
    eval_kernel <<<GE, 256, 0, stream>>>(store, w_eval, b_eval, t_eval, pt,
                                         pos, neg, labeled, partials);
    final_kernel<<<1,  256, 0, stream>>>(partials, out);
}

// Round 6
// 238.209 us; speedup vs baseline: 2.0899x; 1.4471x over previous
//
#include <hip/hip_runtime.h>
#include <math.h>

#define D_    256
#define H_    256
#define R_    8
#define NINIT 8192
#define LL    16
#define MM    4096
#define NTOT  (NINIT + LL*MM)   // 73728
#define TB    16                // nodes per MFMA tile/block
#define MP    (MM + R_*TB)      // 4224 padded slots per layer
#define NB    (MP/TB)           // 264 blocks per layer
#define KS1   16                // K-steps GEMM1 (512/32)
#define KS2   8                 // K-steps GEMM2 (256/32)
#define NT    16                // n-tiles (256/16)
#define EVB   16                // nodes per eval block
#define GE    (NTOT/EVB)        // 4608

#define EMB_BLKS (NINIT*64/256)        // 2048
#define PK1_BLKS (R_*KS1*NT*64/256)    // 512
#define PK2_BLKS (R_*KS2*NT*64/256)    // 256
#define PREP_BLKS (LL + EMB_BLKS + PK1_BLKS + PK2_BLKS)

typedef __attribute__((ext_vector_type(8))) short short8;
typedef __attribute__((ext_vector_type(4))) float f32x4;

__device__ __forceinline__ uint bf16h(float f) {           // f32 -> bf16 bits (RNE)
    uint u = __float_as_uint(f);
    return (u + 0x7fffu + ((u >> 16) & 1u)) >> 16;
}
__device__ __forceinline__ float bf16f(uint h) { return __uint_as_float(h << 16); }

// ---------------- prep bodies ----------------
__device__ void sort_body(int l, int t, const int* __restrict__ rule,
                          int* __restrict__ sorted) {
    __shared__ int hist[R_], cursor[R_];
    if (t < R_) hist[t] = 0;
    __syncthreads();
    for (int m = t; m < MM; m += 256) atomicAdd(&hist[rule[l*MM + m]], 1);
    __syncthreads();
    if (t == 0) {
        int off = 0;
        for (int r = 0; r < R_; r++) { cursor[r] = off; off += ((hist[r] + TB - 1)/TB)*TB; }
    }
    for (int m = t; m < MP; m += 256) sorted[l*MP + m] = -1;
    __syncthreads();
    for (int m = t; m < MM; m += 256) {
        int r = rule[l*MM + m];
        int pos = atomicAdd(&cursor[r], 1);
        sorted[l*MP + pos] = m;
    }
}

__device__ void embed_body(int gid, const float* __restrict__ itab,
                           const float* __restrict__ stab,
                           const int* __restrict__ thax, const int* __restrict__ sine,
                           float* __restrict__ store) {
    int n = gid >> 6, d = (gid & 63) << 2;
    int th = thax[n], si = sine[n];
    const float4 a = *(const float4*)&itab[th*D_ + d];
    const float4 b = *(const float4*)&stab[si*D_ + d];
    float4 o; o.x = a.x+b.x; o.y = a.y+b.y; o.z = a.z+b.z; o.w = a.w+b.w;
    *(float4*)&store[(size_t)n*D_ + d] = o;
}

// Ph[((r*KSn + ks)*NT + nt)*64 + lane][j] = bf16(W[r][ks*32 + (lane>>4)*8 + j][nt*16 + (lane&15)])
__device__ void pack_body(int gid, const float* __restrict__ W,
                          ushort* __restrict__ Ph, int KSn) {
    int lane = gid & 63;
    int nt   = (gid >> 6) & 15;
    int ks   = (gid >> 10) % KSn;
    int r    = gid / (1024*KSn);
    int K = KSn*32;
    int k0 = ks*32 + (lane >> 4)*8;
    int c  = nt*16 + (lane & 15);
    const float* src = W + ((size_t)r*K + k0)*256 + c;
    uint h[8];
    #pragma unroll
    for (int j = 0; j < 8; j++) h[j] = bf16h(src[(size_t)j*256]);
    size_t o = (size_t)gid*8;
    *(uint4*)&Ph[o] = make_uint4(h[0]|(h[1]<<16), h[2]|(h[3]<<16), h[4]|(h[5]<<16), h[6]|(h[7]<<16));
}

__global__ __launch_bounds__(256) void prep_kernel(
        const int* __restrict__ drule, int* __restrict__ sorted,
        const float* __restrict__ itab, const float* __restrict__ stab,
        const int* __restrict__ thax, const int* __restrict__ sine,
        float* __restrict__ store,
        const float* __restrict__ W1, ushort* __restrict__ P1h,
        const float* __restrict__ W2, ushort* __restrict__ P2h) {
    int b = blockIdx.x, t = threadIdx.x;
    if (b < LL) {
        sort_body(b, t, drule, sorted);
    } else if (b < LL + EMB_BLKS) {
        embed_body((b - LL)*256 + t, itab, stab, thax, sine, store);
    } else if (b < LL + EMB_BLKS + PK1_BLKS) {
        pack_body((b - LL - EMB_BLKS)*256 + t, W1, P1h, KS1);
    } else {
        pack_body((b - LL - EMB_BLKS - PK1_BLKS)*256 + t, W2, P2h, KS2);
    }
}

// ---------------- one DAG layer: 16-node tile, 16 waves, 1 n-tile per wave ----------------
// split-bf16 on activations only (xl*Wh + xh*Wh); weights hi-only.
__global__ __launch_bounds__(1024) void layer_kernel(float* __restrict__ store,
        const int* __restrict__ sorted, const int* __restrict__ rule,
        const int* __restrict__ parents,
        const ushort* __restrict__ P1h, const ushort* __restrict__ P2h,
        const float* __restrict__ b1, const float* __restrict__ t1,
        const float* __restrict__ b2, const float* __restrict__ pt, int l) {
    __shared__ ushort Xh[TB*512], Xl[TB*512];   // 16 rows x 512 bf16 hi/lo, swizzled
    __shared__ ushort Hh[TB*256], Hl[TB*256];
    __shared__ int idx_s[TB];
    const int t = threadIdx.x, lane = t & 63, wv = t >> 6;   // wv = 0..15
    if (t < TB) idx_s[t] = sorted[l*MP + blockIdx.x*TB + t];
    __syncthreads();
    if (idx_s[0] < 0) return;                   // fully-padded tail block
    const int r = rule[l*MM + idx_s[0]];
    const float tw = pt[1];

    // ---- stage X: wave wv stages row wv (one parent half per iter, float4/lane) ----
    {
        const int row = wv;
        const int idx = idx_s[row];
        #pragma unroll
        for (int half = 0; half < 2; half++) {
            float4 v = make_float4(0.f, 0.f, 0.f, 0.f);
            if (idx >= 0) {
                int p = parents[(l*MM + idx)*2 + half];
                v = *(const float4*)&store[(size_t)p*D_ + lane*4];
            }
            uint h0 = bf16h(v.x), h1 = bf16h(v.y), h2 = bf16h(v.z), h3 = bf16h(v.w);
            uint l0 = bf16h(v.x - bf16f(h0)), l1 = bf16h(v.y - bf16f(h1));
            uint l2 = bf16h(v.z - bf16f(h2)), l3 = bf16h(v.w - bf16f(h3));
            int e = half*256 + lane*4;
            int boff = (e*2) ^ ((row & 7) << 4);
            *(uint2*)&Xh[row*512 + (boff >> 1)] = make_uint2(h0|(h1<<16), h2|(h3<<16));
            *(uint2*)&Xl[row*512 + (boff >> 1)] = make_uint2(l0|(l1<<16), l2|(l3<<16));
        }
    }
    __syncthreads();

    const int crow = lane & 15, kg = lane >> 4;
    const int col = wv*16 + crow;

    // ---- GEMM1: [16x512] @ W1h[512x256], 2-pass (xl,xh); wave owns n-tile wv ----
    f32x4 acc;
    { float bb = b1[r*H_ + col] + tw * t1[r*H_ + col]; acc = (f32x4){bb, bb, bb, bb}; }
    const short8* B1hp = (const short8*)P1h + ((size_t)r*KS1*NT + wv)*64 + lane;
    #pragma unroll
    for (int ks = 0; ks < KS1; ks++) {
        int ab = ((ks*64 + kg*16) ^ ((crow & 7) << 4)) >> 1;
        short8 xh = *(const short8*)&Xh[crow*512 + ab];
        short8 xl = *(const short8*)&Xl[crow*512 + ab];
        short8 bh = B1hp[(size_t)ks*NT*64];
        acc = __builtin_amdgcn_mfma_f32_16x16x32_bf16(xl, bh, acc, 0, 0, 0);
        acc = __builtin_amdgcn_mfma_f32_16x16x32_bf16(xh, bh, acc, 0, 0, 0);
    }
    // relu + split to bf16 hi/lo H (swizzled)
    #pragma unroll
    for (int reg = 0; reg < 4; reg++) {
        int row = kg*4 + reg;
        float h = fmaxf(acc[reg], 0.f);
        uint hh = bf16h(h);
        uint hl = bf16h(h - bf16f(hh));
        int boff = (col*2) ^ ((row & 7) << 4);
        Hh[row*256 + (boff >> 1)] = (ushort)hh;
        Hl[row*256 + (boff >> 1)] = (ushort)hl;
    }
    __syncthreads();

    // ---- GEMM2: [16x256] @ W2h[256x256], 2-pass (hl,hh); wave owns n-tile wv ----
    f32x4 acc2;
    { float bb = b2[r*D_ + col]; acc2 = (f32x4){bb, bb, bb, bb}; }
    const short8* B2hp = (const short8*)P2h + ((size_t)r*KS2*NT + wv)*64 + lane;
    #pragma unroll
    for (int ks = 0; ks < KS2; ks++) {
        int ab = ((ks*64 + kg*16) ^ ((crow & 7) << 4)) >> 1;
        short8 hh = *(const short8*)&Hh[crow*256 + ab];
        short8 hl = *(const short8*)&Hl[crow*256 + ab];
        short8 bh = B2hp[(size_t)ks*NT*64];
        acc2 = __builtin_amdgcn_mfma_f32_16x16x32_bf16(hl, bh, acc2, 0, 0, 0);
        acc2 = __builtin_amdgcn_mfma_f32_16x16x32_bf16(hh, bh, acc2, 0, 0, 0);
    }
    // ---- store y (f32) ----
    const int ob = NINIT + l*MM;
    #pragma unroll
    for (int reg = 0; reg < 4; reg++) {
        int row = kg*4 + reg;
        int idx = idx_s[row];
        if (idx >= 0) store[(size_t)(ob + idx)*D_ + col] = acc2[reg];
    }
}

// ---------------- eval_net + loss partials ----------------
__global__ __launch_bounds__(256) void eval_kernel(const float* __restrict__ store,
        const float* __restrict__ w_eval, const float* __restrict__ b_eval,
        const float* __restrict__ t_eval, const float* __restrict__ pt,
        const float* __restrict__ pos, const float* __restrict__ neg,
        const int* __restrict__ labeled, float* __restrict__ partials) {
    int t = threadIdx.x, lane = t & 63, wv = t >> 6;
    const float4 w4 = *(const float4*)&w_eval[lane*4];
    const float bev = b_eval[0] + pt[0]*t_eval[0];
    float A = 0.f, B = 0.f, pOK = 0.f, nOK = 0.f, tp = 0.f, tn = 0.f;
    int n0 = blockIdx.x * EVB;
    #pragma unroll
    for (int k = 0; k < 4; k++) {
        int n = n0 + wv*4 + k;
        const float4 s = *(const float4*)&store[(size_t)n*D_ + lane*4];
        float d = s.x*w4.x + s.y*w4.y + s.z*w4.z + s.w*w4.w;
        #pragma unroll
        for (int off = 32; off > 0; off >>= 1) d += __shfl_xor(d, off);
        if (lane == 0) {
            float val = d + bev;
            float lab = (float)labeled[n];
            float p = pos[n], ng = neg[n];
            float tot = p + ng;
            float target = p / fmaxf(tot, 1e-8f);
            float ls  = (val >= 0.f) ? -log1pf(expf(-val)) : (val  - log1pf(expf( val)));
            float lns = (val <= 0.f) ? -log1pf(expf( val)) : (-val - log1pf(expf(-val)));
            A += lab*tot*target*ls;
            B += lab*tot*(1.f - target)*lns;
            if (val >= 0.f) pOK += lab*p; else nOK += lab*ng;
            tp += p*lab; tn += ng*lab;
        }
    }
    __shared__ float red[4][6];
    if (lane == 0) {
        red[wv][0] = A;  red[wv][1] = B;  red[wv][2] = pOK;
        red[wv][3] = nOK; red[wv][4] = tp; red[wv][5] = tn;
    }
    __syncthreads();
    if (t < 6) partials[blockIdx.x*6 + t] = red[0][t] + red[1][t] + red[2][t] + red[3][t];
}

// ---------------- final reduce + pw + loss ----------------
__global__ __launch_bounds__(256) void final_kernel(const float* __restrict__ partials,
                                                    float* __restrict__ out) {
    int t = threadIdx.x;
    float sA=0.f, sB=0.f, sP=0.f, sN=0.f, sTP=0.f, sTN=0.f;
    for (int g = t; g < GE; g += 256) {
        sA  += partials[g*6+0]; sB  += partials[g*6+1]; sP  += partials[g*6+2];
        sN  += partials[g*6+3]; sTP += partials[g*6+4]; sTN += partials[g*6+5];
    }
    __shared__ float red[256];
    #define FRED(V) { __syncthreads(); red[t] = (V); __syncthreads();                     \
        for (int s_ = 128; s_ > 0; s_ >>= 1) { if (t < s_) red[t] += red[t+s_]; __syncthreads(); } \
        (V) = red[0]; __syncthreads(); }
    FRED(sA) FRED(sB) FRED(sP) FRED(sN) FRED(sTP) FRED(sTN)
    #undef FRED
    if (t == 0) {
        float pw = sTN / fmaxf(sTP, 1e-8f);
        out[0] = -(pw*sA + sB);
        out[1] = sP; out[2] = sN; out[3] = sTP; out[4] = sTN;
    }
}

extern "C" void kernel_launch(void* const* d_in, const int* in_sizes, int n_in,
                              void* d_out, int out_size, void* d_ws, size_t ws_size,
                              hipStream_t stream) {
    const float* pt        = (const float*)d_in[0];
    const float* init_tab  = (const float*)d_in[1];
    const float* sine_tab  = (const float*)d_in[2];
    const float* W1        = (const float*)d_in[3];
    const float* b1        = (const float*)d_in[4];
    const float* t1        = (const float*)d_in[5];
    const float* W2        = (const float*)d_in[6];
    const float* b2        = (const float*)d_in[7];
    const float* w_eval    = (const float*)d_in[8];
    const float* b_eval    = (const float*)d_in[9];
    const float* t_eval    = (const float*)d_in[10];
    const float* pos       = (const float*)d_in[11];
    const float* neg       = (const float*)d_in[12];
    const int*   init_thax = (const int*)d_in[13];
    const int*   init_sine = (const int*)d_in[14];
    const int*   drule     = (const int*)d_in[15];
    const int*   dparents  = (const int*)d_in[16];
    const int*   labeled   = (const int*)d_in[17];
    float* out = (float*)d_out;

    // workspace layout (bytes, all 16-aligned)
    char* w = (char*)d_ws;
    const size_t STORE_B = (size_t)NTOT * D_ * 4;            // 75,497,472
    const size_t SORT_B  = (size_t)LL * MP * 4;              //    270,336
    const size_t P1_B    = (size_t)R_*KS1*NT*64*8*2;         //  2,097,152
    const size_t P2_B    = (size_t)R_*KS2*NT*64*8*2;         //  1,048,576
    float*  store    = (float*) w;                    w += STORE_B;
    int*    sorted   = (int*)   w;                    w += SORT_B;
    ushort* P1h      = (ushort*)w;                    w += P1_B;
    ushort* P2h      = (ushort*)w;                    w += P2_B;
    float*  partials = (float*) w;                    // GE*6*4 = 110,592

    prep_kernel<<<PREP_BLKS, 256, 0, stream>>>(drule, sorted, init_tab, sine_tab,
                                               init_thax, init_sine, store,
                                               W1, P1h, W2, P2h);
    for (int l = 0; l < LL; l++)
        layer_kernel<<<NB, 1024, 0, stream>>>(store, sorted, drule, dparents,
                                              P1h, P2h, b1, t1, b2, pt, l);
    eval_kernel <<<GE, 256, 0, stream>>>(store, w_eval, b_eval, t_eval, pt,
                                         pos, neg, labeled, partials);
    final_kernel<<<1,  256, 0, stream>>>(partials, out);
}